// Round 7
// baseline (182.800 us; speedup 1.0000x reference)
//
#include <hip/hip_runtime.h>
#include <hip/hip_bf16.h>

// Hmoe: gate = sigmoid(x @ w + b); tree-product over 6 levels -> P (32768 x 64);
// out = P @ responses.
// Kernel 0 (prep): w -> wFs bf16 hi/lo in MFMA B-fragment order (512 KB);
//   responses -> RTs bf16 in B-fragment order (256 KB).
// Kernel 1 (fused), GBM=16 -> grid 2048 = 8 blocks/CU (32 waves/CU) so
//   block-level TLP hides the per-step barrier/vmcnt latency:
//   phase 1: gate GEMM. x staged via LDS (16 rows, 1 float4/thread/step);
//            w frags read directly from wFs (L2, coalesced). Each wave owns
//            one 16-col group -> 1 acc frag, 4 MFMA/step.
//   phase 2: sigmoid -> gl; tree -> P tile bf16 in LDS (overlays xs)
//   phase 3: out rows = P_tile @ RT, B-frags straight from RTs, no barriers.

typedef short bf16x8 __attribute__((ext_vector_type(8)));
typedef float f32x4  __attribute__((ext_vector_type(4)));

#define BS    32768
#define DIMX  2048
#define NODES 63
#define NL    64
#define DIMY  2048

__device__ __forceinline__ unsigned short f2bf(float f) {
    union { float f; unsigned int u; } v; v.f = f;
    unsigned int r = v.u + 0x7FFFu + ((v.u >> 16) & 1u);   // RNE
    return (unsigned short)(r >> 16);
}
__device__ __forceinline__ float bf2f(unsigned short h) {
    union { float f; unsigned int u; } v; v.u = ((unsigned int)h) << 16;
    return v.f;
}

// ---------------- kernel 0: prep --------------------------------------------
// wFs: frag id = ((k*2 + kk)*4 + g16)*2 + hl ; element (lane l, e 0..7) =
//   wT[node = g16*16 + (l&15)][kcol = k*64 + kk*32 + (l>>4)*8 + e], hi or lo.
// RTs: frag id = nf*2 + kh ; element (l, e) = responses[kh*32+(l>>4)*8+e]
//   [nf*16 + (l&15)].
__global__ __launch_bounds__(256) void prep(const float* __restrict__ w,
                                            const float* __restrict__ R,
                                            unsigned short* __restrict__ wFs,
                                            unsigned short* __restrict__ RTs) {
    int f = blockIdx.x * 256 + threadIdx.x;     // 0..393215
    if (f < 262144) {                           // wFs
        int e   = f & 7;
        int l   = (f >> 3) & 63;
        int hl  = (f >> 9) & 1;
        int g16 = (f >> 10) & 3;
        int kk  = (f >> 12) & 1;
        int k   = f >> 13;                      // 0..31
        int n    = g16 * 16 + (l & 15);
        int kcol = k * 64 + kk * 32 + (l >> 4) * 8 + e;
        float v = (n < NODES) ? w[(size_t)kcol * NODES + n] : 0.0f;
        unsigned short h = f2bf(v);
        wFs[f] = hl ? f2bf(v - bf2f(h)) : h;
    } else {                                    // RTs
        int f2 = f - 262144;
        int e  = f2 & 7;
        int l  = (f2 >> 3) & 63;
        int kh = (f2 >> 9) & 1;
        int nf = f2 >> 10;                      // 0..127
        int k  = kh * 32 + (l >> 4) * 8 + e;    // leaf 0..63
        int n  = nf * 16 + (l & 15);            // dimy col
        RTs[f2] = f2bf(R[(size_t)k * DIMY + n]);
    }
}

// ---------------- kernel 1: fused gates + tree + out -------------------------
#define GBM   16
#define GBK   64
#define GLD   72                    // padded LDS row stride (bf16): 144 B
#define NSTEP (DIMX / GBK)          // 32

__global__ __launch_bounds__(256, 8) void fused_kernel(const float* __restrict__ x,
                                                       const unsigned short* __restrict__ wFs,
                                                       const float* __restrict__ bias,
                                                       const unsigned short* __restrict__ RTs,
                                                       float* __restrict__ out) {
    __shared__ __align__(16) unsigned short xs[GBM][GLD];   // phase1: x / phase3: P
    __shared__ float gl[GBM][NL + 1];

    const int t    = threadIdx.x;
    const int lane = t & 63;
    const int wv   = t >> 6;        // 4 waves; wave wv owns node cols wv*16..+15
    const int lr   = lane & 15;
    const int lg   = lane >> 4;
    const int m0   = blockIdx.x * GBM;

    // ---- phase 1: gate GEMM ----
    const int xr = t >> 4;               // row 0..15
    const int xc = (t & 15) * 4;         // col 0..60
    const float* xsrc = x + (size_t)(m0 + xr) * DIMX + xc;

    const unsigned short* wb = wFs + (size_t)lane * 8;
    #define WFRAG(k, kk, hl) \
        (*(const bf16x8*)(wb + (size_t)((((k) * 2 + (kk)) * 4 + wv) * 2 + (hl)) * 512))

    float4 rx = *(const float4*)(xsrc);

    f32x4 acc = (f32x4){0.f, 0.f, 0.f, 0.f};

    for (int k = 0; k < NSTEP; ++k) {
        __syncthreads();                        // prev step's xs reads done
        {
            union { __hip_bfloat162 h2[2]; ushort4 v; } u;
            u.h2[0] = __float22bfloat162_rn(make_float2(rx.x, rx.y));
            u.h2[1] = __float22bfloat162_rn(make_float2(rx.z, rx.w));
            *(ushort4*)&xs[xr][xc] = u.v;
        }
        __syncthreads();                        // tile visible
        if (k + 1 < NSTEP)
            rx = *(const float4*)(xsrc + (k + 1) * GBK);
        #pragma unroll
        for (int kk = 0; kk < 2; ++kk) {
            bf16x8 a = *(const bf16x8*)&xs[lr][kk * 32 + lg * 8];
            bf16x8 bh = WFRAG(k, kk, 0);
            bf16x8 bo = WFRAG(k, kk, 1);
            acc = __builtin_amdgcn_mfma_f32_16x16x32_bf16(a, bh, acc, 0, 0, 0);
            acc = __builtin_amdgcn_mfma_f32_16x16x32_bf16(a, bo, acc, 0, 0, 0);
        }
    }
    #undef WFRAG

    // ---- phase 2: bias + sigmoid -> gl; tree -> P tile (overlays xs) ----
    {
        const int col = wv * 16 + lr;
        const float bb = bias[col < NODES ? col : 0];   // col 63 unread by tree
        #pragma unroll
        for (int i = 0; i < 4; ++i) {
            float s = acc[i] + bb;
            gl[lg * 4 + i][col] = 1.0f / (1.0f + __expf(-s));
        }
    }
    __syncthreads();                  // gl visible; all xs reads done

    {
        const int rr  = t >> 4;       // 0..15
        const int sub = t & 15;
        const int b5 = sub & 1, b4 = (sub >> 1) & 1, qq = sub >> 2;  // qq 0..3
        const float* g = gl[rr];
        float a2[2], a4[4], a8[8];
        float g0 = g[0];
        a2[0] = g0; a2[1] = 1.f - g0;
        #pragma unroll
        for (int m = 0; m < 4; ++m) {
            float gg = g[1 + (m & 1)];
            a4[m] = a2[m & 1] * ((m & 2) ? (1.f - gg) : gg);
        }
        #pragma unroll
        for (int m = 0; m < 8; ++m) {
            float gg = g[3 + (m & 3)];
            a8[m] = a4[m & 3] * ((m & 4) ? (1.f - gg) : gg);
        }
        unsigned short o[4];
        #pragma unroll
        for (int j = 0; j < 4; ++j) {
            int m = qq * 4 + j;                   // 0..15
            float g4 = g[7 + (m & 7)];
            float p  = a8[m & 7] * ((m & 8) ? (1.f - g4) : g4);
            float g5 = g[15 + m];
            p *= b4 ? (1.f - g5) : g5;
            float g6 = g[31 + m + 16 * b4];
            p *= b5 ? (1.f - g6) : g6;
            o[j] = f2bf(p);
        }
        uint2 qv;
        qv.x = (unsigned)o[0] | ((unsigned)o[1] << 16);
        qv.y = (unsigned)o[2] | ((unsigned)o[3] << 16);
        *(uint2*)&xs[rr][b5 * 32 + b4 * 16 + qq * 4] = qv;   // P tile
    }
    __syncthreads();                  // P tile visible

    // ---- phase 3: out rows = P_tile @ RT, no barriers ----
    bf16x8 pa[2];
    #pragma unroll
    for (int kh = 0; kh < 2; ++kh)
        pa[kh] = *(const bf16x8*)&xs[lr][kh * 32 + lg * 8];

    const unsigned short* bbase = RTs + (size_t)lane * 8;
    #define BLD(s, ci, kh) \
        (*(const bf16x8*)(bbase + (size_t)((((s) * 8 + wv * 2 + (ci)) * 2 + (kh))) * 512))

    float* op = out + (size_t)(m0 + lg * 4) * DIMY + wv * 32 + lr;

    #pragma unroll
    for (int s = 0; s < 16; ++s) {
        bf16x8 c00 = BLD(s, 0, 0), c01 = BLD(s, 0, 1);
        bf16x8 c10 = BLD(s, 1, 0), c11 = BLD(s, 1, 1);
        f32x4 oa0 = (f32x4){0.f, 0.f, 0.f, 0.f};
        f32x4 oa1 = (f32x4){0.f, 0.f, 0.f, 0.f};
        oa0 = __builtin_amdgcn_mfma_f32_16x16x32_bf16(pa[0], c00, oa0, 0, 0, 0);
        oa0 = __builtin_amdgcn_mfma_f32_16x16x32_bf16(pa[1], c01, oa0, 0, 0, 0);
        oa1 = __builtin_amdgcn_mfma_f32_16x16x32_bf16(pa[0], c10, oa1, 0, 0, 0);
        oa1 = __builtin_amdgcn_mfma_f32_16x16x32_bf16(pa[1], c11, oa1, 0, 0, 0);
        #pragma unroll
        for (int i = 0; i < 4; ++i) {
            op[(size_t)i * DIMY + s * 128]      = oa0[i];
            op[(size_t)i * DIMY + s * 128 + 16] = oa1[i];
        }
    }
    #undef BLD
}

extern "C" void kernel_launch(void* const* d_in, const int* in_sizes, int n_in,
                              void* d_out, int out_size, void* d_ws, size_t ws_size,
                              hipStream_t stream) {
    const float* x = (const float*)d_in[0];
    const float* w = (const float*)d_in[1];
    const float* b = (const float*)d_in[2];
    const float* R = (const float*)d_in[3];
    float* out = (float*)d_out;

    char* ws = (char*)d_ws;
    unsigned short* wFs = (unsigned short*)ws;                  // 512 KB
    unsigned short* RTs = (unsigned short*)(ws + 524288);       // 256 KB

    prep<<<dim3(1536), 256, 0, stream>>>(w, R, wFs, RTs);
    fused_kernel<<<dim3(BS / GBM), 256, 0, stream>>>(x, wFs, b, RTs, out);
}

// Round 8
// 161.042 us; speedup vs baseline: 1.1351x; 1.1351x over previous
//
#include <hip/hip_runtime.h>
#include <hip/hip_bf16.h>

// Hmoe: gate = sigmoid(x @ w + b); tree-product over 6 levels -> P (32768 x 64);
// out = P @ responses.
// prep: w -> wFs bf16 hi/lo in MFMA B-fragment order (512 KB);
//       responses -> RTs bf16 in B-fragment order (256 KB).
// fused v6 — ZERO barriers in all hot loops (out_kernel structure everywhere):
//   block = 128 thr = 2 waves, one 16-row group per block, split-K across waves.
//   phase 1: each wave loads its own rows' x coalescedly (128B-line groups),
//            cvt_pk to bf16 in regs, redistributes to A-frag layout via
//            __shfl (ds_bpermute, wave-local, no barrier, no LDS tile);
//            w B-frags stream from wFs (L2). 16 MFMA / step, no syncthreads.
//   phase 2: combine split-K logit partials (barrier #1), sigmoid+tree ->
//            P tile in LDS (barrier #2).
//   phase 3: out = P_tile @ RT; B-frags stream from RTs; waves split cols;
//            barrier-free, stream stores.

typedef short bf16x8 __attribute__((ext_vector_type(8)));
typedef float f32x4  __attribute__((ext_vector_type(4)));

#define BS    32768
#define DIMX  2048
#define NODES 63
#define NL    64
#define DIMY  2048

__device__ __forceinline__ unsigned short f2bf(float f) {
    union { float f; unsigned int u; } v; v.f = f;
    unsigned int r = v.u + 0x7FFFu + ((v.u >> 16) & 1u);   // RNE
    return (unsigned short)(r >> 16);
}
__device__ __forceinline__ float bf2f(unsigned short h) {
    union { float f; unsigned int u; } v; v.u = ((unsigned int)h) << 16;
    return v.f;
}

// ---------------- kernel 0: prep --------------------------------------------
// wFs: frag id = ((k*2 + kk)*4 + g16)*2 + hl ; element (lane l, e 0..7) =
//   wT[node = g16*16 + (l&15)][kcol = k*64 + kk*32 + (l>>4)*8 + e], hi or lo.
// RTs: frag id = nf*2 + kh ; element (l, e) = responses[kh*32+(l>>4)*8+e]
//   [nf*16 + (l&15)].
__global__ __launch_bounds__(256) void prep(const float* __restrict__ w,
                                            const float* __restrict__ R,
                                            unsigned short* __restrict__ wFs,
                                            unsigned short* __restrict__ RTs) {
    int f = blockIdx.x * 256 + threadIdx.x;     // 0..393215
    if (f < 262144) {                           // wFs
        int e   = f & 7;
        int l   = (f >> 3) & 63;
        int hl  = (f >> 9) & 1;
        int g16 = (f >> 10) & 3;
        int kk  = (f >> 12) & 1;
        int k   = f >> 13;                      // 0..31
        int n    = g16 * 16 + (l & 15);
        int kcol = k * 64 + kk * 32 + (l >> 4) * 8 + e;
        float v = (n < NODES) ? w[(size_t)kcol * NODES + n] : 0.0f;
        unsigned short h = f2bf(v);
        wFs[f] = hl ? f2bf(v - bf2f(h)) : h;
    } else {                                    // RTs
        int f2 = f - 262144;
        int e  = f2 & 7;
        int l  = (f2 >> 3) & 63;
        int kh = (f2 >> 9) & 1;
        int nf = f2 >> 10;                      // 0..127
        int k  = kh * 32 + (l >> 4) * 8 + e;    // leaf 0..63
        int n  = nf * 16 + (l & 15);            // dimy col
        RTs[f2] = f2bf(R[(size_t)k * DIMY + n]);
    }
}

// ---------------- kernel 1: fused gates + tree + out -------------------------
#define GBM 16      // rows per block (one 16-row MFMA group)

__global__ __launch_bounds__(128, 4) void fused_kernel(const float* __restrict__ x,
                                                       const unsigned short* __restrict__ wFs,
                                                       const float* __restrict__ bias,
                                                       const unsigned short* __restrict__ RTs,
                                                       float* __restrict__ out) {
    __shared__ float bl[NL];
    __shared__ float glp[2][GBM][NL + 1];                   // split-K logit partials
    __shared__ __align__(16) unsigned short pt[GBM][72];    // P tile (pad: 144B rows)

    const int t    = threadIdx.x;
    const int lane = t & 63;
    const int wv   = t >> 6;        // 2 waves: split-K halves / col halves
    const int lr   = lane & 15;
    const int lg   = lane >> 4;
    const int m0   = blockIdx.x * GBM;

    if (t < NL) bl[t] = (t < NODES) ? bias[t] : 0.0f;

    // ---- phase 1: gate GEMM, barrier-free ----
    // x load map: lane (r = lane>>2, c = lane&3) reads row r, k = c*8..+8 and
    // 32+c*8..+8 per 64-wide step -> 4 float4, each instr = 16 full 128B lines.
    const int xr = lane >> 2;
    const int xc = lane & 3;
    const float* xw = x + (size_t)(m0 + xr) * DIMX + xc * 8;
    const int srcl = (lr << 2) | lg;            // shfl source lane for A-frags
    const unsigned short* wb = wFs + (size_t)lane * 8;

    f32x4 acc[4];
    #pragma unroll
    for (int g = 0; g < 4; ++g) acc[g] = (f32x4){0.f, 0.f, 0.f, 0.f};

    const int kbeg = wv * 16;                   // this wave's K half (16 steps)
    #pragma unroll 2
    for (int ks = 0; ks < 16; ++ks) {
        const int k = kbeg + ks;
        const float* xk = xw + (size_t)k * 64;
        float4 v0 = *(const float4*)(xk);
        float4 v1 = *(const float4*)(xk + 4);
        float4 v2 = *(const float4*)(xk + 32);
        float4 v3 = *(const float4*)(xk + 36);
        int q[8];
        {
            union { __hip_bfloat162 h; int i; } u;
            u.h = __float22bfloat162_rn(make_float2(v0.x, v0.y)); q[0] = u.i;
            u.h = __float22bfloat162_rn(make_float2(v0.z, v0.w)); q[1] = u.i;
            u.h = __float22bfloat162_rn(make_float2(v1.x, v1.y)); q[2] = u.i;
            u.h = __float22bfloat162_rn(make_float2(v1.z, v1.w)); q[3] = u.i;
            u.h = __float22bfloat162_rn(make_float2(v2.x, v2.y)); q[4] = u.i;
            u.h = __float22bfloat162_rn(make_float2(v2.z, v2.w)); q[5] = u.i;
            u.h = __float22bfloat162_rn(make_float2(v3.x, v3.y)); q[6] = u.i;
            u.h = __float22bfloat162_rn(make_float2(v3.z, v3.w)); q[7] = u.i;
        }
        union { int i[4]; bf16x8 v; } A0, A1;
        #pragma unroll
        for (int j = 0; j < 4; ++j) {
            A0.i[j] = __shfl(q[j], srcl);       // wave-local redistribute
            A1.i[j] = __shfl(q[4 + j], srcl);   // (ds_bpermute, no barrier)
        }
        #pragma unroll
        for (int g = 0; g < 4; ++g) {
            const size_t b0 = (size_t)(((k * 2 + 0) * 4 + g) * 2) * 512;
            const size_t b1 = (size_t)(((k * 2 + 1) * 4 + g) * 2) * 512;
            bf16x8 bh0 = *(const bf16x8*)(wb + b0);
            bf16x8 bo0 = *(const bf16x8*)(wb + b0 + 512);
            bf16x8 bh1 = *(const bf16x8*)(wb + b1);
            bf16x8 bo1 = *(const bf16x8*)(wb + b1 + 512);
            acc[g] = __builtin_amdgcn_mfma_f32_16x16x32_bf16(A0.v, bh0, acc[g], 0, 0, 0);
            acc[g] = __builtin_amdgcn_mfma_f32_16x16x32_bf16(A0.v, bo0, acc[g], 0, 0, 0);
            acc[g] = __builtin_amdgcn_mfma_f32_16x16x32_bf16(A1.v, bh1, acc[g], 0, 0, 0);
            acc[g] = __builtin_amdgcn_mfma_f32_16x16x32_bf16(A1.v, bo1, acc[g], 0, 0, 0);
        }
    }

    // write split-K logit partials.  D-frag: row=lg*4+i, col=g*16+lr.
    #pragma unroll
    for (int g = 0; g < 4; ++g)
        #pragma unroll
        for (int i = 0; i < 4; ++i)
            glp[wv][lg * 4 + i][g * 16 + lr] = acc[g][i];
    __syncthreads();                  // barrier #1: partials + bl visible

    // ---- phase 2: sigmoid + tree -> P tile.  Wave wv: rows wv*8..+8,
    //      8 lanes/row, each lane 8 leaves. ----
    {
        const int rr  = wv * 8 + (lane >> 3);
        const int sub = lane & 7;
        const int b5 = sub & 1, b4 = (sub >> 1) & 1, mh = sub >> 2;
        const float* p0 = glp[0][rr];
        const float* p1 = glp[1][rr];
        #define G(c) (1.0f / (1.0f + __expf(-(p0[c] + p1[c] + bl[c]))))
        float a2[2], a4[4], a8[8];
        float g0 = G(0);
        a2[0] = g0; a2[1] = 1.f - g0;
        #pragma unroll
        for (int m = 0; m < 4; ++m) {
            float gg = G(1 + (m & 1));
            a4[m] = a2[m & 1] * ((m & 2) ? (1.f - gg) : gg);
        }
        #pragma unroll
        for (int m = 0; m < 8; ++m) {
            float gg = G(3 + (m & 3));
            a8[m] = a4[m & 3] * ((m & 4) ? (1.f - gg) : gg);
        }
        unsigned short o[8];
        #pragma unroll
        for (int j = 0; j < 8; ++j) {
            int m = mh * 8 + j;                   // 0..15
            float g4 = G(7 + (m & 7));
            float p  = a8[m & 7] * ((m & 8) ? (1.f - g4) : g4);
            float g5 = G(15 + m);
            p *= b4 ? (1.f - g5) : g5;
            float g6 = G(31 + m + 16 * b4);
            p *= b5 ? (1.f - g6) : g6;
            o[j] = f2bf(p);
        }
        #undef G
        uint4 q;
        q.x = (unsigned)o[0] | ((unsigned)o[1] << 16);
        q.y = (unsigned)o[2] | ((unsigned)o[3] << 16);
        q.z = (unsigned)o[4] | ((unsigned)o[5] << 16);
        q.w = (unsigned)o[6] | ((unsigned)o[7] << 16);
        *(uint4*)&pt[rr][b5 * 32 + b4 * 16 + mh * 8] = q;
    }
    __syncthreads();                  // barrier #2: P tile visible

    // ---- phase 3: out rows = P_tile @ RT, barrier-free; wave wv covers
    //      col-frags nf = wv*64 .. +64 ----
    bf16x8 pa0 = *(const bf16x8*)&pt[lr][lg * 8];
    bf16x8 pa1 = *(const bf16x8*)&pt[lr][32 + lg * 8];
    const unsigned short* rb = RTs + (size_t)lane * 8;
    float* op = out + (size_t)(m0 + lg * 4) * DIMY + lr;

    const int nfb = wv * 64;
    #pragma unroll 4
    for (int s = 0; s < 64; ++s) {
        const int nf = nfb + s;
        bf16x8 c0 = *(const bf16x8*)(rb + (size_t)(nf * 2) * 512);
        bf16x8 c1 = *(const bf16x8*)(rb + (size_t)(nf * 2 + 1) * 512);
        f32x4 oa = (f32x4){0.f, 0.f, 0.f, 0.f};
        oa = __builtin_amdgcn_mfma_f32_16x16x32_bf16(pa0, c0, oa, 0, 0, 0);
        oa = __builtin_amdgcn_mfma_f32_16x16x32_bf16(pa1, c1, oa, 0, 0, 0);
        #pragma unroll
        for (int i = 0; i < 4; ++i)
            op[(size_t)i * DIMY + nf * 16] = oa[i];
    }
}

extern "C" void kernel_launch(void* const* d_in, const int* in_sizes, int n_in,
                              void* d_out, int out_size, void* d_ws, size_t ws_size,
                              hipStream_t stream) {
    const float* x = (const float*)d_in[0];
    const float* w = (const float*)d_in[1];
    const float* b = (const float*)d_in[2];
    const float* R = (const float*)d_in[3];
    float* out = (float*)d_out;

    char* ws = (char*)d_ws;
    unsigned short* wFs = (unsigned short*)ws;                  // 512 KB
    unsigned short* RTs = (unsigned short*)(ws + 524288);       // 256 KB

    prep<<<dim3(1536), 256, 0, stream>>>(w, R, wFs, RTs);
    fused_kernel<<<dim3(BS / GBM), 128, 0, stream>>>(x, wFs, b, RTs, out);
}